// Round 1
// baseline (166.373 us; speedup 1.0000x reference)
//
#include <hip/hip_runtime.h>

// out[b] = (x @ W^T).sum(axis=1) * (0.5 * 2.0)
//        = sum_k x[b,k] * wsum[k],   wsum[k] = sum_h W[h,k]
// Two memory-bound passes instead of an O(N^3) fp32 GEMM (no fp32 MFMA on CDNA4).

#define N 4096            // BATCH == INPUT_SIZE == HIDDEN_SIZE
#define N4 (N / 4)        // float4 elements per row
#define ROWS_PER_BLOCK 16

// Pass 1: wsum[k] = sum_h W[h,k].  W is (HIDDEN, INPUT) row-major.
// grid.x tiles columns (256 threads x float4 = 1024 cols/tile -> 4 tiles),
// grid.y tiles rows (16 rows/block -> 256 tiles). 1024 blocks total.
__global__ __launch_bounds__(256) void colsum_kernel(
    const float* __restrict__ W, float* __restrict__ wsum) {
    const int col4 = blockIdx.x * 256 + threadIdx.x;       // float4 column index
    const int row0 = blockIdx.y * ROWS_PER_BLOCK;
    const float4* __restrict__ W4 = (const float4*)W;

    float4 acc = make_float4(0.f, 0.f, 0.f, 0.f);
#pragma unroll
    for (int r = 0; r < ROWS_PER_BLOCK; ++r) {
        float4 v = W4[(size_t)(row0 + r) * N4 + col4];     // coalesced: 256 consecutive float4/wave-iter
        acc.x += v.x; acc.y += v.y; acc.z += v.z; acc.w += v.w;
    }
    float* dst = wsum + 4 * col4;
    atomicAdd(dst + 0, acc.x);
    atomicAdd(dst + 1, acc.y);
    atomicAdd(dst + 2, acc.z);
    atomicAdd(dst + 3, acc.w);
}

// Pass 2: out[b] = dot(x[b,:], wsum) * 1.0f.  One 256-thread block per row.
__global__ __launch_bounds__(256) void rowdot_kernel(
    const float* __restrict__ x, const float* __restrict__ wsum,
    float* __restrict__ out) {
    const int b = blockIdx.x;
    const float4* __restrict__ x4 = (const float4*)(x + (size_t)b * N);
    const float4* __restrict__ w4 = (const float4*)wsum;

    float acc = 0.f;
#pragma unroll
    for (int i = threadIdx.x; i < N4; i += 256) {
        float4 xv = x4[i];
        float4 wv = w4[i];
        acc += xv.x * wv.x + xv.y * wv.y + xv.z * wv.z + xv.w * wv.w;
    }

    // wave64 shuffle reduction
#pragma unroll
    for (int off = 32; off > 0; off >>= 1)
        acc += __shfl_down(acc, off, 64);

    __shared__ float s[4];
    if ((threadIdx.x & 63) == 0) s[threadIdx.x >> 6] = acc;
    __syncthreads();
    if (threadIdx.x == 0)
        out[b] = (s[0] + s[1] + s[2] + s[3]) * (0.5f * 2.0f);
}

extern "C" void kernel_launch(void* const* d_in, const int* in_sizes, int n_in,
                              void* d_out, int out_size, void* d_ws, size_t ws_size,
                              hipStream_t stream) {
    const float* x = (const float*)d_in[0];       // (4096, 4096) fp32
    const float* W = (const float*)d_in[1];       // (4096, 4096) fp32
    float* out = (float*)d_out;                   // (4096, 1) fp32
    float* wsum = (float*)d_ws;                   // 4096 fp32 scratch

    // d_ws is re-poisoned to 0xAA before every timed launch: zero it each call.
    hipMemsetAsync(wsum, 0, N * sizeof(float), stream);

    dim3 grid1(N4 / 256, N / ROWS_PER_BLOCK);     // (4, 256) = 1024 blocks
    colsum_kernel<<<grid1, 256, 0, stream>>>(W, wsum);

    rowdot_kernel<<<N, 256, 0, stream>>>(x, wsum, out);
}

// Round 2
// 149.241 us; speedup vs baseline: 1.1148x; 1.1148x over previous
//
#include <hip/hip_runtime.h>

// out[b] = (x @ W^T).sum(axis=1) * (0.5 * 2.0) = sum_k x[b,k] * wsum[k],
// with wsum[k] = sum_h W[h,k].
// Three deterministic memory-bound passes; NO atomics (R1 showed 256-way
// atomicAdd contention made colsum 3x slower than its BW floor).

#define N 4096            // BATCH == INPUT_SIZE == HIDDEN_SIZE
#define N4 (N / 4)        // float4 elements per row
#define P 128             // row partitions for partial column sums
#define ROWS (N / P)      // 32 rows per partial block

// Stage 1: partial[p][k] = sum over 32 rows of W[., k].  Plain stores, no atomics.
// grid (4, 128) = 512 blocks (2/CU); each thread owns one float4 column,
// 32 independent dwordx4 loads -> deep MLP, coalesced 1 KiB/wave/iter.
__global__ __launch_bounds__(256) void colsum_partial_kernel(
    const float* __restrict__ W, float* __restrict__ partial) {
    const int col4 = blockIdx.x * 256 + threadIdx.x;
    const int row0 = blockIdx.y * ROWS;
    const float4* __restrict__ W4 = (const float4*)W;

    float4 acc = make_float4(0.f, 0.f, 0.f, 0.f);
#pragma unroll
    for (int r = 0; r < ROWS; ++r) {
        float4 v = W4[(size_t)(row0 + r) * N4 + col4];
        acc.x += v.x; acc.y += v.y; acc.z += v.z; acc.w += v.w;
    }
    ((float4*)partial)[(size_t)blockIdx.y * N4 + col4] = acc;
}

// Stage 2: wsum[k] = sum_p partial[p][k].  4 blocks x 256 threads, 2 MB read.
__global__ __launch_bounds__(256) void colsum_reduce_kernel(
    const float* __restrict__ partial, float* __restrict__ wsum) {
    const int col4 = blockIdx.x * 256 + threadIdx.x;
    const float4* __restrict__ p4 = (const float4*)partial;

    float4 acc = make_float4(0.f, 0.f, 0.f, 0.f);
#pragma unroll
    for (int p = 0; p < P; ++p) {
        float4 v = p4[(size_t)p * N4 + col4];
        acc.x += v.x; acc.y += v.y; acc.z += v.z; acc.w += v.w;
    }
    ((float4*)wsum)[col4] = acc;
}

// Stage 3: out[b] = dot(x[b,:], wsum).  One 256-thread block per row.
__global__ __launch_bounds__(256) void rowdot_kernel(
    const float* __restrict__ x, const float* __restrict__ wsum,
    float* __restrict__ out) {
    const int b = blockIdx.x;
    const float4* __restrict__ x4 = (const float4*)(x + (size_t)b * N);
    const float4* __restrict__ w4 = (const float4*)wsum;

    float acc = 0.f;
#pragma unroll
    for (int i = threadIdx.x; i < N4; i += 256) {
        float4 xv = x4[i];
        float4 wv = w4[i];
        acc += xv.x * wv.x + xv.y * wv.y + xv.z * wv.z + xv.w * wv.w;
    }

    // wave64 shuffle reduction
#pragma unroll
    for (int off = 32; off > 0; off >>= 1)
        acc += __shfl_down(acc, off, 64);

    __shared__ float s[4];
    if ((threadIdx.x & 63) == 0) s[threadIdx.x >> 6] = acc;
    __syncthreads();
    if (threadIdx.x == 0)
        out[b] = (s[0] + s[1] + s[2] + s[3]) * (0.5f * 2.0f);
}

extern "C" void kernel_launch(void* const* d_in, const int* in_sizes, int n_in,
                              void* d_out, int out_size, void* d_ws, size_t ws_size,
                              hipStream_t stream) {
    const float* x = (const float*)d_in[0];       // (4096, 4096) fp32
    const float* W = (const float*)d_in[1];       // (4096, 4096) fp32
    float* out = (float*)d_out;                   // (4096, 1) fp32

    float* partial = (float*)d_ws;                            // P * N floats = 2 MiB
    float* wsum = (float*)((char*)d_ws + (size_t)P * N * 4);  // N floats, 16B-aligned

    dim3 grid1(N4 / 256, P);                      // (4, 128) = 512 blocks
    colsum_partial_kernel<<<grid1, 256, 0, stream>>>(W, partial);

    colsum_reduce_kernel<<<N4 / 256, 256, 0, stream>>>(partial, wsum);

    rowdot_kernel<<<N, 256, 0, stream>>>(x, wsum, out);
}